// Round 7
// baseline (148.291 us; speedup 1.0000x reference)
//
#include <hip/hip_runtime.h>

// out[n, h*28+w] = cos(pi * x[n,2h,2w] / (m[h,w] + 1e-8)),
// m[h,w] = max_n max(x[n,2h,2w], x[n,2h,2w+1]).
// (Unit-modulus phases + CNOT perm leave the Z0 expectation = cos(t0);
//  params/phases/permutation cancel exactly.)
//
// TWO dispatches:
//  K1: 1024 blocks x 8 images -> partial maxima M[1024][784] (float4 loads,
//      float2 plain stores). Completion-counter tail: the last 98 finisher
//      blocks spin until all 1024 are done (safe without co-residency: they
//      wait only on blocks that never wait), then do the coalesced column
//      reduce (784 cols x 32 groups of 32 rows) + atomicMax into mu.
//  K2: 4 outputs/thread: 2x float4 x-load (L3-hot), float4 out-store.

namespace {

constexpr int IMG  = 3136;   // 56*56 floats / image
constexpr int HW   = 784;    // 28*28 outputs / image
constexpr int NIMG = 8192;
constexpr int NB1  = 1024;
constexpr int IPB  = NIMG / NB1;   // 8 images / K1 block
constexpr int RED_BLOCKS = 98;     // 25088 reduce threads = 784 cols x 32 groups

__global__ __launch_bounds__(256) void k_partial(const float* __restrict__ x,
                                                 float* __restrict__ M,
                                                 unsigned* __restrict__ mu,
                                                 unsigned* __restrict__ cnt) {
    const int t = threadIdx.x;
    const int b = blockIdx.x;

    // float4 slot u covers row 2h, cols 4w..4w+3 = output positions 2u, 2u+1
    const int h0 = t / 14,  w0 = t - h0 * 14,  o0 = h0 * 112 + w0 * 4;
    const int u1 = t + 256;
    const int h1 = u1 / 14, w1 = u1 - h1 * 14, o1 = h1 * 112 + w1 * 4;
    const bool a1 = (u1 < 392);

    float2 lm0 = make_float2(0.f, 0.f);
    float2 lm1 = make_float2(0.f, 0.f);

    const float* base = x + (size_t)b * IPB * IMG;
#pragma unroll
    for (int n = 0; n < IPB; ++n) {
        const float* p = base + (size_t)n * IMG;
        float4 v = *(const float4*)(p + o0);
        lm0.x = fmaxf(lm0.x, fmaxf(v.x, v.y));
        lm0.y = fmaxf(lm0.y, fmaxf(v.z, v.w));
        if (a1) {
            float4 w = *(const float4*)(p + o1);
            lm1.x = fmaxf(lm1.x, fmaxf(w.x, w.y));
            lm1.y = fmaxf(lm1.y, fmaxf(w.z, w.w));
        }
    }

    *(float2*)(M + (size_t)b * HW + 2 * t) = lm0;
    if (a1) *(float2*)(M + (size_t)b * HW + 2 * u1) = lm1;

    // ---- completion-counter tail ----
    __threadfence();                 // agent-scope release of the M stores
    __syncthreads();                 // all threads' stores + fences retired

    __shared__ int rank;
    if (t == 0)
        rank = (int)__hip_atomic_fetch_add(cnt, 1u, __ATOMIC_ACQ_REL,
                                           __HIP_MEMORY_SCOPE_AGENT);
    __syncthreads();

    const int r = rank - (NB1 - RED_BLOCKS);
    if (r < 0) return;               // not among the last finishers

    while (__hip_atomic_load(cnt, __ATOMIC_ACQUIRE, __HIP_MEMORY_SCOPE_AGENT) < NB1)
        __builtin_amdgcn_s_sleep(8);

    // coalesced column reduce: u = (group g, col); 32 rows per group
    const int u   = r * 256 + t;            // 0..25087
    const int g   = u / HW;
    const int col = u - g * HW;
    const float* mp = M + (size_t)(g * 32) * HW + col;
    float cm = 0.f;
#pragma unroll
    for (int k = 0; k < 32; ++k)
        cm = fmaxf(cm, mp[(size_t)k * HW]);
    atomicMax(mu + col, __float_as_uint(cm));  // positive: uint cmp == float cmp
}

// 4 outputs/thread. cos(pi*u) = v_cos(u*0.5) [revolutions], u in [0,1].
__global__ __launch_bounds__(256) void k_out(const float* __restrict__ x,
                                             const float* __restrict__ mu,
                                             float* __restrict__ out) {
    int g  = blockIdx.x * 256 + threadIdx.x;
    int n  = g / 196;
    int j  = g - n * 196;       // output float4 index within image
    int h  = j / 7;
    int wq = j - h * 7;         // out cols 4wq..4wq+3

    const float* p = x + (size_t)n * IMG + h * 112 + 8 * wq;
    float4 va = *(const float4*)p;
    float4 vb = *(const float4*)(p + 4);

    const float* mp = mu + h * 28 + 4 * wq;
    float2 ma = *(const float2*)mp;
    float2 mb = *(const float2*)(mp + 2);

    float4 o;
    o.x = __builtin_amdgcn_cosf(va.x * (0.5f / (ma.x + 1e-8f)));
    o.y = __builtin_amdgcn_cosf(va.z * (0.5f / (ma.y + 1e-8f)));
    o.z = __builtin_amdgcn_cosf(vb.x * (0.5f / (mb.x + 1e-8f)));
    o.w = __builtin_amdgcn_cosf(vb.z * (0.5f / (mb.y + 1e-8f)));

    *(float4*)(out + (size_t)n * HW + 4 * j) = o;
}

} // namespace

extern "C" void kernel_launch(void* const* d_in, const int* in_sizes, int n_in,
                              void* d_out, int out_size, void* d_ws, size_t ws_size,
                              hipStream_t stream) {
    const float* x   = (const float*)d_in[0];
    float*       M   = (float*)d_ws;                                    // 1024*784 f
    unsigned*    mu  = (unsigned*)((char*)d_ws + (size_t)NB1 * HW * 4); // 784
    unsigned*    cnt = mu + HW;                                         // 1 counter
    float*       out = (float*)d_out;

    hipMemsetAsync(mu, 0, (HW + 1) * sizeof(unsigned), stream);  // mu + cnt
    hipLaunchKernelGGL(k_partial, dim3(NB1), dim3(256), 0, stream, x, M, mu, cnt);
    hipLaunchKernelGGL(k_out, dim3(NIMG * 196 / 256), dim3(256), 0, stream,
                       x, (const float*)mu, out);
}

// Round 8
// 86.850 us; speedup vs baseline: 1.7074x; 1.7074x over previous
//
#include <hip/hip_runtime.h>

// out[n, h*28+w] = cos(pi * x[n,2h,2w] / (m[h,w] + 1e-8)),
// m[h,w] = max_n max(x[n,2h,2w], x[n,2h,2w+1]).
// (Unit-modulus phases + CNOT perm leave the Z0 expectation = cos(t0);
//  params/phases/permutation cancel exactly.)
//
// ONE persistent kernel, FENCE-FREE grid barrier (R7 lesson: __threadfence on
// gfx950 = buffer_wbl2 per-XCD L2 flush = disaster; fine-grained agent-scope
// atomics execute at the Infinity Cache and need no flush):
//  phase 1: 1024 blocks x 8 images, float4 loads of even rows; p0 kept in
//           registers (32 floats/thread); per-block maxima -> 4 relaxed
//           agent atomicMax into mu2[b&7][pos] (128 RMW chains/address).
//  barrier: s_waitcnt vmcnt(0); one atomicAdd per block; spin on relaxed
//           agent atomic loads (sc1 -> always fresh from IC; no inv needed
//           since all shared data is read via sc1 too).
//  phase 3: max over the 8 copies (sc1 loads), cos via v_cos (revolutions),
//           dense float2 stores. x read exactly once; no fences anywhere.
// Co-residency: __launch_bounds__(256,4) caps VGPR at 128 (kernel ~60) ->
// 4 blocks/CU x 256 CUs = 1024 blocks all resident; barrier cannot deadlock.

namespace {

constexpr int IMG   = 3136;        // 56*56 floats / image
constexpr int HW    = 784;         // 28*28 outputs / image
constexpr int NIMG  = 8192;
constexpr int NB    = 1024;
constexpr int IPB   = NIMG / NB;   // 8 images / block
constexpr int NCOPY = 8;           // mu2 slices

#define AGENT __HIP_MEMORY_SCOPE_AGENT

__global__ __launch_bounds__(256, 4)
void k_fused(const float* __restrict__ x, unsigned* __restrict__ mu2,
             unsigned* __restrict__ cnt, float* __restrict__ out)
{
    const int t  = threadIdx.x;
    const int b  = blockIdx.x;

    // float4 slot u covers row 2h, cols 4w..4w+3 = output positions 2u, 2u+1
    const int h0 = t / 14,  w0 = t - h0 * 14,  o0 = h0 * 112 + w0 * 4;
    const int u1 = t + 256;
    const int h1 = u1 / 14, w1 = u1 - h1 * 14, o1 = h1 * 112 + w1 * 4;
    const bool a1 = (u1 < 392);

    float pa0[IPB], pa1[IPB], pb0[IPB], pb1[IPB];
    float2 lm0 = make_float2(0.f, 0.f), lm1 = make_float2(0.f, 0.f);

    // ---- phase 1: read even rows once, p0 stays in registers ----
    const float* base = x + (size_t)b * IPB * IMG;
#pragma unroll
    for (int n = 0; n < IPB; ++n) {
        const float* p = base + (size_t)n * IMG;
        float4 v = *(const float4*)(p + o0);
        pa0[n] = v.x; pa1[n] = v.z;
        lm0.x = fmaxf(lm0.x, fmaxf(v.x, v.y));
        lm0.y = fmaxf(lm0.y, fmaxf(v.z, v.w));
        if (a1) {
            float4 w = *(const float4*)(p + o1);
            pb0[n] = w.x; pb1[n] = w.z;
            lm1.x = fmaxf(lm1.x, fmaxf(w.x, w.y));
            lm1.y = fmaxf(lm1.y, fmaxf(w.z, w.w));
        }
    }

    // per-block maxima -> sliced global max (positive floats: uint cmp == float cmp)
    unsigned* row = mu2 + (size_t)(b & (NCOPY - 1)) * HW;
    __hip_atomic_fetch_max(row + 2 * t,     __float_as_uint(lm0.x), __ATOMIC_RELAXED, AGENT);
    __hip_atomic_fetch_max(row + 2 * t + 1, __float_as_uint(lm0.y), __ATOMIC_RELAXED, AGENT);
    if (a1) {
        __hip_atomic_fetch_max(row + 2 * u1,     __float_as_uint(lm1.x), __ATOMIC_RELAXED, AGENT);
        __hip_atomic_fetch_max(row + 2 * u1 + 1, __float_as_uint(lm1.y), __ATOMIC_RELAXED, AGENT);
    }

    // ---- fence-free grid barrier ----
    asm volatile("s_waitcnt vmcnt(0)" ::: "memory");  // my RMWs are at the IC
    __syncthreads();                                  // whole block's RMWs done
    if (t == 0) {
        __hip_atomic_fetch_add(cnt, 1u, __ATOMIC_RELAXED, AGENT);
        while (__hip_atomic_load(cnt, __ATOMIC_RELAXED, AGENT) < (unsigned)NB)
            __builtin_amdgcn_s_sleep(2);
    }
    __syncthreads();

    // ---- phase 3: reduce the 8 copies (sc1 loads), cos, store ----
    unsigned m0 = 0, m1 = 0, m2 = 0, m3 = 0;
#pragma unroll
    for (int r = 0; r < NCOPY; ++r) {
        const unsigned* rp = mu2 + (size_t)r * HW;
        m0 = max(m0, __hip_atomic_load(rp + 2 * t,     __ATOMIC_RELAXED, AGENT));
        m1 = max(m1, __hip_atomic_load(rp + 2 * t + 1, __ATOMIC_RELAXED, AGENT));
        if (a1) {
            m2 = max(m2, __hip_atomic_load(rp + 2 * u1,     __ATOMIC_RELAXED, AGENT));
            m3 = max(m3, __hip_atomic_load(rp + 2 * u1 + 1, __ATOMIC_RELAXED, AGENT));
        }
    }
    const float ra0 = 0.5f / (__uint_as_float(m0) + 1e-8f);  // cos(pi*u)=v_cos(u/2)
    const float ra1 = 0.5f / (__uint_as_float(m1) + 1e-8f);
    const float rb0 = 0.5f / (__uint_as_float(m2) + 1e-8f);
    const float rb1 = 0.5f / (__uint_as_float(m3) + 1e-8f);

    float* ob = out + (size_t)b * IPB * HW;
#pragma unroll
    for (int n = 0; n < IPB; ++n) {
        float2 oa;
        oa.x = __builtin_amdgcn_cosf(pa0[n] * ra0);
        oa.y = __builtin_amdgcn_cosf(pa1[n] * ra1);
        *(float2*)(ob + (size_t)n * HW + 2 * t) = oa;
        if (a1) {
            float2 ov;
            ov.x = __builtin_amdgcn_cosf(pb0[n] * rb0);
            ov.y = __builtin_amdgcn_cosf(pb1[n] * rb1);
            *(float2*)(ob + (size_t)n * HW + 2 * u1) = ov;
        }
    }
}

} // namespace

extern "C" void kernel_launch(void* const* d_in, const int* in_sizes, int n_in,
                              void* d_out, int out_size, void* d_ws, size_t ws_size,
                              hipStream_t stream) {
    const float* x   = (const float*)d_in[0];
    unsigned*    mu2 = (unsigned*)d_ws;        // 8*784 uints
    unsigned*    cnt = mu2 + NCOPY * HW;       // 1 counter
    float*       out = (float*)d_out;

    hipMemsetAsync(mu2, 0, (NCOPY * HW + 1) * sizeof(unsigned), stream);
    hipLaunchKernelGGL(k_fused, dim3(NB), dim3(256), 0, stream, x, mu2, cnt, out);
}

// Round 9
// 53.232 us; speedup vs baseline: 2.7858x; 1.6315x over previous
//
#include <hip/hip_runtime.h>

// out[n, h*28+w] = cos(pi * x[n,2h,2w] / (m[h,w] + 1e-8)),
// m[h,w] = max_n max(x[n,2h,2w], x[n,2h,2w+1]).
// (Unit-modulus phases + CNOT perm leave the Z0 expectation = cos(t0);
//  params/phases/permutation cancel exactly.)
//
// TWO dispatches (+1 tiny memset):
//  K1: 1024 blocks x 8 images (R4's proven hot loop, float4 loads). Partial
//      maxima written to M[1024][784] via RELAXED AGENT-SCOPE ATOMIC STORES
//      (write-through to Infinity Cache -- NO __threadfence, no buffer_wbl2;
//      R7 lesson). Then s_waitcnt vmcnt(0) + one atomicAdd rank per block;
//      the last 98 finisher blocks (lane-0 spin; they wait only on blocks
//      that never wait -> no co-residency requirement) run K2's coalesced
//      column reduce (784 cols x 32 groups of 32 rows) + atomicMax into mu.
//  K2: R4's k_out unchanged: 4 outputs/thread, 2x float4 x-load (L3-hot),
//      float4 out-store.

namespace {

constexpr int IMG  = 3136;   // 56*56 floats / image
constexpr int HW   = 784;    // 28*28 outputs / image
constexpr int NIMG = 8192;
constexpr int NB1  = 1024;
constexpr int IPB  = NIMG / NB1;   // 8 images / K1 block
constexpr int RED_BLOCKS = 98;     // 25088 reduce threads = 784 cols x 32 groups

#define AGENT __HIP_MEMORY_SCOPE_AGENT

__global__ __launch_bounds__(256) void k_partial(const float* __restrict__ x,
                                                 unsigned* __restrict__ M,
                                                 unsigned* __restrict__ mu,
                                                 unsigned* __restrict__ cnt) {
    const int t = threadIdx.x;
    const int b = blockIdx.x;

    // float4 slot u covers row 2h, cols 4w..4w+3 = output positions 2u, 2u+1
    const int h0 = t / 14,  w0 = t - h0 * 14,  o0 = h0 * 112 + w0 * 4;
    const int u1 = t + 256;
    const int h1 = u1 / 14, w1 = u1 - h1 * 14, o1 = h1 * 112 + w1 * 4;
    const bool a1 = (u1 < 392);

    float2 lm0 = make_float2(0.f, 0.f);
    float2 lm1 = make_float2(0.f, 0.f);

    const float* base = x + (size_t)b * IPB * IMG;
#pragma unroll
    for (int n = 0; n < IPB; ++n) {
        const float* p = base + (size_t)n * IMG;
        float4 v = *(const float4*)(p + o0);
        lm0.x = fmaxf(lm0.x, fmaxf(v.x, v.y));
        lm0.y = fmaxf(lm0.y, fmaxf(v.z, v.w));
        if (a1) {
            float4 w = *(const float4*)(p + o1);
            lm1.x = fmaxf(lm1.x, fmaxf(w.x, w.y));
            lm1.y = fmaxf(lm1.y, fmaxf(w.z, w.w));
        }
    }

    // partials -> M via write-through agent atomic stores (IC-visible, no fence)
    unsigned* Mb = M + (size_t)b * HW;
    __hip_atomic_store(Mb + 2 * t,     __float_as_uint(lm0.x), __ATOMIC_RELAXED, AGENT);
    __hip_atomic_store(Mb + 2 * t + 1, __float_as_uint(lm0.y), __ATOMIC_RELAXED, AGENT);
    if (a1) {
        __hip_atomic_store(Mb + 2 * u1,     __float_as_uint(lm1.x), __ATOMIC_RELAXED, AGENT);
        __hip_atomic_store(Mb + 2 * u1 + 1, __float_as_uint(lm1.y), __ATOMIC_RELAXED, AGENT);
    }

    // ---- completion-counter tail (fence-free) ----
    asm volatile("s_waitcnt vmcnt(0)" ::: "memory");  // my stores acked at IC
    __syncthreads();                                  // whole block's stores done

    __shared__ unsigned rank;
    if (t == 0)
        rank = __hip_atomic_fetch_add(cnt, 1u, __ATOMIC_RELAXED, AGENT);
    __syncthreads();

    const int r = (int)rank - (NB1 - RED_BLOCKS);
    if (r < 0) return;                // not a finisher

    if (t == 0) {
        while (__hip_atomic_load(cnt, __ATOMIC_RELAXED, AGENT) < (unsigned)NB1)
            __builtin_amdgcn_s_sleep(4);
    }
    __syncthreads();

    // K2's reduce: u = (group g, col); 32 rows per group, coalesced cols
    const int u   = r * 256 + t;            // 0..25087
    const int g   = u / HW;
    const int col = u - g * HW;
    const unsigned* mp = M + (size_t)(g * 32) * HW + col;
    unsigned cm = 0u;
#pragma unroll
    for (int k = 0; k < 32; ++k)
        cm = max(cm, __hip_atomic_load(mp + (size_t)k * HW, __ATOMIC_RELAXED, AGENT));
    atomicMax(mu + col, cm);   // positive floats: uint cmp == float cmp
}

// 4 outputs/thread. cos(pi*u) = v_cos(u*0.5) [revolutions], u in [0,1].
__global__ __launch_bounds__(256) void k_out(const float* __restrict__ x,
                                             const float* __restrict__ mu,
                                             float* __restrict__ out) {
    int g  = blockIdx.x * 256 + threadIdx.x;
    int n  = g / 196;
    int j  = g - n * 196;       // output float4 index within image
    int h  = j / 7;
    int wq = j - h * 7;         // out cols 4wq..4wq+3

    const float* p = x + (size_t)n * IMG + h * 112 + 8 * wq;
    float4 va = *(const float4*)p;
    float4 vb = *(const float4*)(p + 4);

    const float* mp = mu + h * 28 + 4 * wq;
    float2 ma = *(const float2*)mp;
    float2 mb = *(const float2*)(mp + 2);

    float4 o;
    o.x = __builtin_amdgcn_cosf(va.x * (0.5f / (ma.x + 1e-8f)));
    o.y = __builtin_amdgcn_cosf(va.z * (0.5f / (ma.y + 1e-8f)));
    o.z = __builtin_amdgcn_cosf(vb.x * (0.5f / (mb.x + 1e-8f)));
    o.w = __builtin_amdgcn_cosf(vb.z * (0.5f / (mb.y + 1e-8f)));

    *(float4*)(out + (size_t)n * HW + 4 * j) = o;
}

} // namespace

extern "C" void kernel_launch(void* const* d_in, const int* in_sizes, int n_in,
                              void* d_out, int out_size, void* d_ws, size_t ws_size,
                              hipStream_t stream) {
    const float* x   = (const float*)d_in[0];
    unsigned*    mu  = (unsigned*)d_ws;                       // 784
    unsigned*    cnt = mu + HW;                               // 1
    unsigned*    M   = (unsigned*)((char*)d_ws + 4096);       // 1024*784 u32
    float*       out = (float*)d_out;

    // zero mu + cnt every call (ws poisoned 0xAA once; cnt must restart at 0)
    hipMemsetAsync(mu, 0, (HW + 1) * sizeof(unsigned), stream);
    hipLaunchKernelGGL(k_partial, dim3(NB1), dim3(256), 0, stream, x, M, mu, cnt);
    hipLaunchKernelGGL(k_out, dim3(NIMG * 196 / 256), dim3(256), 0, stream,
                       x, (const float*)mu, out);
}

// Round 11
// 37.466 us; speedup vs baseline: 3.9580x; 1.4208x over previous
//
#include <hip/hip_runtime.h>

// out[n, h*28+w] = cos(pi * x[n,2h,2w] / (m[h,w] + 1e-8)),
// m[h,w] = max_n max(x[n,2h,2w], x[n,2h,2w+1]).
// (Unit-modulus phases + CNOT perm leave the Z0 expectation = cos(t0);
//  params/phases/permutation cancel exactly.)
//
// R4 champion structure (3 dispatches, no fences, no cross-block waits),
// with k_out tuned only:
//  K1: 1024 blocks x 8 images -> partial maxima M[1024][784] (float4 loads,
//      float2 plain stores); block 0 zeroes mu.
//  K2: 784 cols x 32 groups of 32 rows, coalesced; 32 atomicMax per col.
//  K3: 2 images x 4 outputs per thread (4 independent float4 loads, more MLP),
//      NON-TEMPORAL stores via native ext_vector_type (HIP_vector_type is
//      rejected by __builtin_nontemporal_store).

namespace {

typedef float vf4 __attribute__((ext_vector_type(4)));

constexpr int IMG  = 3136;   // 56*56 floats / image
constexpr int HW   = 784;    // 28*28 outputs / image
constexpr int NIMG = 8192;
constexpr int NB1  = 1024;
constexpr int IPB  = NIMG / NB1;  // 8 images / K1 block

__global__ __launch_bounds__(256) void k_partial(const float* __restrict__ x,
                                                 float* __restrict__ M,
                                                 unsigned* __restrict__ mu) {
    const int t = threadIdx.x;
    const int b = blockIdx.x;

    if (b == 0) {   // zero mu for K2's atomics (ws poisoned 0xAA)
        for (int i = t; i < HW; i += 256) mu[i] = 0u;
    }

    // float4 slot u covers row 2h, cols 4w..4w+3 = output positions 2u, 2u+1
    const int h0 = t / 14,  w0 = t - h0 * 14,  o0 = h0 * 112 + w0 * 4;
    const int u1 = t + 256;
    const int h1 = u1 / 14, w1 = u1 - h1 * 14, o1 = h1 * 112 + w1 * 4;
    const bool a1 = (u1 < 392);

    float2 lm0 = make_float2(0.f, 0.f);
    float2 lm1 = make_float2(0.f, 0.f);

    const float* base = x + (size_t)b * IPB * IMG;
#pragma unroll
    for (int n = 0; n < IPB; ++n) {
        const float* p = base + (size_t)n * IMG;
        float4 v = *(const float4*)(p + o0);
        lm0.x = fmaxf(lm0.x, fmaxf(v.x, v.y));
        lm0.y = fmaxf(lm0.y, fmaxf(v.z, v.w));
        if (a1) {
            float4 w = *(const float4*)(p + o1);
            lm1.x = fmaxf(lm1.x, fmaxf(w.x, w.y));
            lm1.y = fmaxf(lm1.y, fmaxf(w.z, w.w));
        }
    }

    *(float2*)(M + (size_t)b * HW + 2 * t) = lm0;
    if (a1) *(float2*)(M + (size_t)b * HW + 2 * u1) = lm1;
}

// 784 cols x 32 groups of 32 rows = 25088 threads (98 blocks, exact).
__global__ __launch_bounds__(256) void k_final(const float* __restrict__ M,
                                               unsigned* __restrict__ mu) {
    int u = blockIdx.x * 256 + threadIdx.x;
    int g   = u / HW;
    int col = u - g * HW;
    const float* p = M + (size_t)g * 32 * HW + col;
    float cm = 0.0f;
#pragma unroll
    for (int k = 0; k < 32; ++k)
        cm = fmaxf(cm, p[k * HW]);
    atomicMax(mu + col, __float_as_uint(cm));  // positive floats: uint cmp == float cmp
}

// 2 images x 4 outputs per thread. cos(pi*u) = v_cos(u*0.5) [revolutions].
// 4096*196 = 802,816 threads = 3136 blocks (exact).
__global__ __launch_bounds__(256) void k_out(const float* __restrict__ x,
                                             const float* __restrict__ mu,
                                             float* __restrict__ out) {
    int g  = blockIdx.x * 256 + threadIdx.x;
    int n  = g / 196;           // image in [0,4096); pair image = n+4096
    int j  = g - n * 196;       // output float4 index within image
    int h  = j / 7;
    int wq = j - h * 7;         // out cols 4wq..4wq+3

    const float* p  = x + (size_t)n * IMG + h * 112 + 8 * wq;
    const float* p2 = p + (size_t)4096 * IMG;
    float4 va = *(const float4*)p;
    float4 vb = *(const float4*)(p + 4);
    float4 vc = *(const float4*)p2;
    float4 vd = *(const float4*)(p2 + 4);

    const float* mp = mu + h * 28 + 4 * wq;
    float2 ma = *(const float2*)mp;
    float2 mb = *(const float2*)(mp + 2);
    const float r0 = 0.5f / (ma.x + 1e-8f);
    const float r1 = 0.5f / (ma.y + 1e-8f);
    const float r2 = 0.5f / (mb.x + 1e-8f);
    const float r3 = 0.5f / (mb.y + 1e-8f);

    vf4 o, o2;
    o.x  = __builtin_amdgcn_cosf(va.x * r0);
    o.y  = __builtin_amdgcn_cosf(va.z * r1);
    o.z  = __builtin_amdgcn_cosf(vb.x * r2);
    o.w  = __builtin_amdgcn_cosf(vb.z * r3);
    o2.x = __builtin_amdgcn_cosf(vc.x * r0);
    o2.y = __builtin_amdgcn_cosf(vc.z * r1);
    o2.z = __builtin_amdgcn_cosf(vd.x * r2);
    o2.w = __builtin_amdgcn_cosf(vd.z * r3);

    __builtin_nontemporal_store(o,  (vf4*)(out + (size_t)n * HW + 4 * j));
    __builtin_nontemporal_store(o2, (vf4*)(out + (size_t)(n + 4096) * HW + 4 * j));
}

} // namespace

extern "C" void kernel_launch(void* const* d_in, const int* in_sizes, int n_in,
                              void* d_out, int out_size, void* d_ws, size_t ws_size,
                              hipStream_t stream) {
    const float* x   = (const float*)d_in[0];
    float*       M   = (float*)d_ws;                                    // 1024*784 f
    unsigned*    mu  = (unsigned*)((char*)d_ws + (size_t)NB1 * HW * 4); // 784
    float*       out = (float*)d_out;

    hipLaunchKernelGGL(k_partial, dim3(NB1), dim3(256), 0, stream, x, M, mu);
    hipLaunchKernelGGL(k_final, dim3(HW * 32 / 256), dim3(256), 0, stream, M, mu);
    hipLaunchKernelGGL(k_out, dim3(4096 * 196 / 256), dim3(256), 0, stream,
                       x, (const float*)mu, out);
}